// Round 1
// baseline (9678.105 us; speedup 1.0000x reference)
//
#include <hip/hip_runtime.h>
#include <hip/hip_bf16.h>

#define HID 128
#define NH  4          // heads
#define FEAT (NH*HID)  // 512 per node per projection
#define NEG_SLOPE 0.2f
#define BN_EPS 1e-5f

// ---------- helpers ----------
__device__ inline unsigned mapf(float f) {
    unsigned u = __float_as_uint(f);
    return (u & 0x80000000u) ? ~u : (u | 0x80000000u);
}
__device__ inline float unmapf(unsigned u) {
    return __uint_as_float((u & 0x80000000u) ? (u & 0x7fffffffu) : ~u);
}

// ---------- f32 tiled GEMM: C[M,Nc] = A[M,K] @ B[K,Nc] ----------
// BM=BN=64, BK=16, 256 threads, 4x4 microtile. K % 16 == 0, Nc % 64 == 0.
__global__ __launch_bounds__(256) void gemm_f32(const float* __restrict__ A,
                                                const float* __restrict__ B,
                                                float* __restrict__ C,
                                                int M, int Nc, int K)
{
    __shared__ float As[16][64];   // transposed: As[k][row]
    __shared__ float Bs[16][64];
    const int bm = blockIdx.x * 64;
    const int bn = blockIdx.y * 64;
    const int tid = threadIdx.x;
    const int tx = tid & 15, ty = tid >> 4;
    float acc[4][4] = {};
    for (int k0 = 0; k0 < K; k0 += 16) {
        // A tile: 64 rows x 16 k, each thread one float4 along k
        {
            int r = tid >> 2;            // 0..63
            int c = (tid & 3) << 2;      // 0,4,8,12
            int gr = bm + r;
            float4 av = make_float4(0.f, 0.f, 0.f, 0.f);
            if (gr < M) av = *(const float4*)(A + (size_t)gr * K + k0 + c);
            As[c + 0][r] = av.x; As[c + 1][r] = av.y;
            As[c + 2][r] = av.z; As[c + 3][r] = av.w;
        }
        // B tile: 16 k x 64 cols
        {
            int r = tid >> 4;            // 0..15
            int c = (tid & 15) << 2;     // 0..60
            float4 bv = *(const float4*)(B + (size_t)(k0 + r) * Nc + bn + c);
            *(float4*)&Bs[r][c] = bv;
        }
        __syncthreads();
        #pragma unroll
        for (int kk = 0; kk < 16; ++kk) {
            float4 a4 = *(const float4*)&As[kk][ty << 2];
            float4 b4 = *(const float4*)&Bs[kk][tx << 2];
            float a_[4] = {a4.x, a4.y, a4.z, a4.w};
            float b_[4] = {b4.x, b4.y, b4.z, b4.w};
            #pragma unroll
            for (int i = 0; i < 4; ++i)
                #pragma unroll
                for (int j = 0; j < 4; ++j)
                    acc[i][j] += a_[i] * b_[j];
        }
        __syncthreads();
    }
    #pragma unroll
    for (int i = 0; i < 4; ++i) {
        int gr = bm + (ty << 2) + i;
        if (gr < M) {
            float4 v = make_float4(acc[i][0], acc[i][1], acc[i][2], acc[i][3]);
            *(float4*)(C + (size_t)gr * Nc + bn + (tx << 2)) = v;
        }
    }
}

// ---------- edge pass A: logits + segment max ----------
// one wave (64 lanes) per edge; lane covers 8 consecutive floats of the
// 512-wide (H*HID) row -> head = lane/16.
__global__ __launch_bounds__(256) void edge_logits(const float* __restrict__ xl,
                                                   const float* __restrict__ xr,
                                                   const int* __restrict__ ei,
                                                   const float* __restrict__ att,
                                                   float* __restrict__ logit_out,
                                                   unsigned* __restrict__ lmax,
                                                   int E, int Etot)
{
    int gw = (blockIdx.x * 256 + threadIdx.x) >> 6;
    int lane = threadIdx.x & 63;
    if (gw >= Etot) return;
    int src, dst;
    if (gw < E) { src = ei[gw]; dst = ei[E + gw]; }
    else        { src = dst = gw - E; }

    const float4* xls = (const float4*)(xl + (size_t)src * FEAT) + lane * 2;
    const float4* xrs = (const float4*)(xr + (size_t)dst * FEAT) + lane * 2;
    const float4* at4 = (const float4*)att + lane * 2;
    float4 a0 = xls[0], a1 = xls[1];
    float4 b0 = xrs[0], b1 = xrs[1];
    float4 t0 = at4[0], t1 = at4[1];

    float xa[8] = {a0.x, a0.y, a0.z, a0.w, a1.x, a1.y, a1.z, a1.w};
    float xb[8] = {b0.x, b0.y, b0.z, b0.w, b1.x, b1.y, b1.z, b1.w};
    float tt[8] = {t0.x, t0.y, t0.z, t0.w, t1.x, t1.y, t1.z, t1.w};
    float s = 0.f;
    #pragma unroll
    for (int k = 0; k < 8; ++k) {
        float v = xa[k] + xb[k];
        v = (v > 0.f) ? v : NEG_SLOPE * v;
        s += v * tt[k];
    }
    // reduce within 16-lane group (one head each)
    #pragma unroll
    for (int off = 1; off < 16; off <<= 1) s += __shfl_xor(s, off, 64);

    if ((lane & 15) == 0) {
        int head = lane >> 4;
        logit_out[(size_t)gw * NH + head] = s;
        atomicMax(&lmax[dst * NH + head], mapf(s));
    }
}

// ---------- edge pass B: exp + segment sum ----------
__global__ __launch_bounds__(256) void edge_expsum(float* __restrict__ logit_ex,
                                                   const int* __restrict__ ei,
                                                   const unsigned* __restrict__ lmax,
                                                   float* __restrict__ denom,
                                                   int E, int Etot)
{
    int i = blockIdx.x * 256 + threadIdx.x;
    if (i >= Etot * NH) return;
    int e = i >> 2, h = i & 3;
    int dst = (e < E) ? ei[E + e] : (e - E);
    float m = unmapf(lmax[dst * NH + h]);
    float ex = expf(logit_ex[i] - m);
    logit_ex[i] = ex;
    atomicAdd(&denom[dst * NH + h], ex);
}

// ---------- edge pass C: normalize alpha + weighted scatter ----------
__global__ __launch_bounds__(256) void edge_scatter(const float* __restrict__ xl,
                                                    float* __restrict__ alpha,
                                                    const int* __restrict__ ei,
                                                    const float* __restrict__ denom,
                                                    float* __restrict__ acc,
                                                    int E, int Etot)
{
    int gw = (blockIdx.x * 256 + threadIdx.x) >> 6;
    int lane = threadIdx.x & 63;
    if (gw >= Etot) return;
    int src, dst;
    if (gw < E) { src = ei[gw]; dst = ei[E + gw]; }
    else        { src = dst = gw - E; }
    int head = lane >> 4;
    float ex = alpha[(size_t)gw * NH + head];
    float d  = denom[dst * NH + head];
    float al = ex / (d + 1e-16f);
    if ((lane & 15) == 0) alpha[(size_t)gw * NH + head] = al;

    const float4* xls = (const float4*)(xl + (size_t)src * FEAT) + lane * 2;
    float* accp = acc + (size_t)dst * FEAT + lane * 8;
    float4 v0 = xls[0], v1 = xls[1];
    atomicAdd(accp + 0, al * v0.x);
    atomicAdd(accp + 1, al * v0.y);
    atomicAdd(accp + 2, al * v0.z);
    atomicAdd(accp + 3, al * v0.w);
    atomicAdd(accp + 4, al * v1.x);
    atomicAdd(accp + 5, al * v1.y);
    atomicAdd(accp + 6, al * v1.z);
    atomicAdd(accp + 7, al * v1.w);
}

// ---------- node pass: mean heads + bias + BN + ReLU ----------
__global__ __launch_bounds__(256) void node_bn(const float* __restrict__ acc,
                                               const float* __restrict__ bias,
                                               const float* __restrict__ g,
                                               const float* __restrict__ be,
                                               const float* __restrict__ m,
                                               const float* __restrict__ v,
                                               float* __restrict__ hout, int N)
{
    int i = blockIdx.x * 256 + threadIdx.x;
    if (i >= N * HID) return;
    int n = i >> 7, c = i & 127;
    const float* a = acc + (size_t)n * FEAT;
    float s = (a[c] + a[HID + c] + a[2 * HID + c] + a[3 * HID + c]) * 0.25f + bias[c];
    float bn = (s - m[c]) * rsqrtf(v[c] + BN_EPS) * g[c] + be[c];
    hout[i] = fmaxf(bn, 0.f);
}

// ---------- final linear + relu + sigmoid: one wave per node ----------
__global__ __launch_bounds__(256) void final_lin(const float* __restrict__ h,
                                                 const float* __restrict__ W,
                                                 const float* __restrict__ b,
                                                 float* __restrict__ out, int N)
{
    int gw = (blockIdx.x * 256 + threadIdx.x) >> 6;
    int lane = threadIdx.x & 63;
    if (gw >= N) return;
    const float* hp = h + (size_t)gw * HID;
    float s = hp[lane] * W[lane] + hp[64 + lane] * W[64 + lane];
    #pragma unroll
    for (int off = 1; off < 64; off <<= 1) s += __shfl_xor(s, off, 64);
    if (lane == 0) {
        float z = fmaxf(s + b[0], 0.f);
        out[gw] = 1.f / (1.f + expf(-z));
    }
}

extern "C" void kernel_launch(void* const* d_in, const int* in_sizes, int n_in,
                              void* d_out, int out_size, void* d_ws, size_t ws_size,
                              hipStream_t stream)
{
    const float* x    = (const float*)d_in[0];
    const int*   ei   = (const int*)d_in[1];
    const float* Wl1  = (const float*)d_in[2];
    const float* Wr1  = (const float*)d_in[3];
    const float* att1 = (const float*)d_in[4];
    const float* b1   = (const float*)d_in[5];
    const float* Wl2  = (const float*)d_in[6];
    const float* Wr2  = (const float*)d_in[7];
    const float* att2 = (const float*)d_in[8];
    const float* b2   = (const float*)d_in[9];
    const float* g1   = (const float*)d_in[10];
    const float* be1  = (const float*)d_in[11];
    const float* m1   = (const float*)d_in[12];
    const float* v1   = (const float*)d_in[13];
    const float* g2   = (const float*)d_in[14];
    const float* be2  = (const float*)d_in[15];
    const float* m2   = (const float*)d_in[16];
    const float* v2   = (const float*)d_in[17];
    const float* Wlin = (const float*)d_in[18];
    const float* blin = (const float*)d_in[19];

    const int IN_C = 256;
    const int N = in_sizes[0] / IN_C;       // 10000
    const int E = in_sizes[1] / 2;          // 320000
    const int Etot = E + N;                 // with self loops

    float* out    = (float*)d_out;          // [N]
    float* alpha1 = out + N;                // [Etot*NH]
    float* alpha2 = alpha1 + (size_t)Etot * NH;

    // workspace layout (floats)
    float*    ws    = (float*)d_ws;
    unsigned* lmax  = (unsigned*)ws;                       // N*NH
    float*    denom = ws + (size_t)N * NH;                 // N*NH
    float*    acc   = ws + (size_t)N * NH * 2;             // N*FEAT
    float*    xl    = acc + (size_t)N * FEAT;              // N*FEAT
    float*    xr    = xl  + (size_t)N * FEAT;              // N*FEAT
    float*    hbuf  = xr  + (size_t)N * FEAT;              // N*HID

    const size_t zero_bytes = ((size_t)N * NH * 2 + (size_t)N * FEAT) * sizeof(float);

    dim3 blk(256);
    dim3 gemm_grid((N + 63) / 64, FEAT / 64);
    int edge_wave_blocks = (Etot + 3) / 4;       // 1 wave per edge, 4 waves/block
    int eh_blocks = (Etot * NH + 255) / 256;
    int node_blocks = (N * HID + 255) / 256;
    int final_blocks = (N + 3) / 4;

    // ================= layer 1 =================
    hipMemsetAsync(d_ws, 0, zero_bytes, stream);
    gemm_f32<<<gemm_grid, blk, 0, stream>>>(x, Wl1, xl, N, FEAT, IN_C);
    gemm_f32<<<gemm_grid, blk, 0, stream>>>(x, Wr1, xr, N, FEAT, IN_C);
    edge_logits<<<edge_wave_blocks, blk, 0, stream>>>(xl, xr, ei, att1, alpha1, lmax, E, Etot);
    edge_expsum<<<eh_blocks, blk, 0, stream>>>(alpha1, ei, lmax, denom, E, Etot);
    edge_scatter<<<edge_wave_blocks, blk, 0, stream>>>(xl, alpha1, ei, denom, acc, E, Etot);
    node_bn<<<node_blocks, blk, 0, stream>>>(acc, b1, g1, be1, m1, v1, hbuf, N);

    // ================= layer 2 =================
    hipMemsetAsync(d_ws, 0, zero_bytes, stream);
    gemm_f32<<<gemm_grid, blk, 0, stream>>>(hbuf, Wl2, xl, N, FEAT, HID);
    gemm_f32<<<gemm_grid, blk, 0, stream>>>(hbuf, Wr2, xr, N, FEAT, HID);
    edge_logits<<<edge_wave_blocks, blk, 0, stream>>>(xl, xr, ei, att2, alpha2, lmax, E, Etot);
    edge_expsum<<<eh_blocks, blk, 0, stream>>>(alpha2, ei, lmax, denom, E, Etot);
    edge_scatter<<<edge_wave_blocks, blk, 0, stream>>>(xl, alpha2, ei, denom, acc, E, Etot);
    node_bn<<<node_blocks, blk, 0, stream>>>(acc, b2, g2, be2, m2, v2, hbuf, N);

    // ================= head =================
    final_lin<<<final_blocks, blk, 0, stream>>>(hbuf, Wlin, blin, out, N);
}

// Round 2
// 763.804 us; speedup vs baseline: 12.6709x; 12.6709x over previous
//
#include <hip/hip_runtime.h>
#include <hip/hip_bf16.h>

#define HID 128
#define NH  4          // heads
#define FEAT (NH*HID)  // 512 per node per projection
#define NEG_SLOPE 0.2f
#define BN_EPS 1e-5f

// ---------- helpers ----------
__device__ inline unsigned mapf(float f) {
    unsigned u = __float_as_uint(f);
    return (u & 0x80000000u) ? ~u : (u | 0x80000000u);
}
__device__ inline float unmapf(unsigned u) {
    return __uint_as_float((u & 0x80000000u) ? (u & 0x7fffffffu) : ~u);
}

// ---------- f32 tiled GEMM: C[M,Nc] = A[M,K] @ B[K,Nc] ----------
__global__ __launch_bounds__(256) void gemm_f32(const float* __restrict__ A,
                                                const float* __restrict__ B,
                                                float* __restrict__ C,
                                                int M, int Nc, int K)
{
    __shared__ float As[16][64];   // transposed: As[k][row]
    __shared__ float Bs[16][64];
    const int bm = blockIdx.x * 64;
    const int bn = blockIdx.y * 64;
    const int tid = threadIdx.x;
    const int tx = tid & 15, ty = tid >> 4;
    float acc[4][4] = {};
    for (int k0 = 0; k0 < K; k0 += 16) {
        {
            int r = tid >> 2;
            int c = (tid & 3) << 2;
            int gr = bm + r;
            float4 av = make_float4(0.f, 0.f, 0.f, 0.f);
            if (gr < M) av = *(const float4*)(A + (size_t)gr * K + k0 + c);
            As[c + 0][r] = av.x; As[c + 1][r] = av.y;
            As[c + 2][r] = av.z; As[c + 3][r] = av.w;
        }
        {
            int r = tid >> 4;
            int c = (tid & 15) << 2;
            float4 bv = *(const float4*)(B + (size_t)(k0 + r) * Nc + bn + c);
            *(float4*)&Bs[r][c] = bv;
        }
        __syncthreads();
        #pragma unroll
        for (int kk = 0; kk < 16; ++kk) {
            float4 a4 = *(const float4*)&As[kk][ty << 2];
            float4 b4 = *(const float4*)&Bs[kk][tx << 2];
            float a_[4] = {a4.x, a4.y, a4.z, a4.w};
            float b_[4] = {b4.x, b4.y, b4.z, b4.w};
            #pragma unroll
            for (int i = 0; i < 4; ++i)
                #pragma unroll
                for (int j = 0; j < 4; ++j)
                    acc[i][j] += a_[i] * b_[j];
        }
        __syncthreads();
    }
    #pragma unroll
    for (int i = 0; i < 4; ++i) {
        int gr = bm + (ty << 2) + i;
        if (gr < M) {
            float4 v = make_float4(acc[i][0], acc[i][1], acc[i][2], acc[i][3]);
            *(float4*)(C + (size_t)gr * Nc + bn + (tx << 2)) = v;
        }
    }
}

// ---------- CSR build ----------
__global__ __launch_bounds__(256) void csr_count(const int* __restrict__ ei,
                                                 int* __restrict__ deg,
                                                 int E, int Etot)
{
    int i = blockIdx.x * 256 + threadIdx.x;
    if (i >= Etot) return;
    int dst = (i < E) ? ei[E + i] : (i - E);
    atomicAdd(&deg[dst], 1);
}

// single block, 1024 threads: exclusive scan of deg -> rowptr, cursor
__global__ __launch_bounds__(1024) void scan_rowptr(const int* __restrict__ deg,
                                                    int* __restrict__ rowptr,
                                                    int* __restrict__ cursor,
                                                    int N)
{
    __shared__ int part[1024];
    int t = threadIdx.x;
    int chunk = (N + 1023) / 1024;
    int lo = t * chunk;
    int hi = lo + chunk; if (hi > N) hi = N; if (lo > N) lo = N;
    int s = 0;
    for (int i = lo; i < hi; ++i) s += deg[i];
    part[t] = s;
    __syncthreads();
    for (int off = 1; off < 1024; off <<= 1) {
        int v = (t >= off) ? part[t - off] : 0;
        __syncthreads();
        part[t] += v;
        __syncthreads();
    }
    int base = (t == 0) ? 0 : part[t - 1];
    for (int i = lo; i < hi; ++i) {
        rowptr[i] = base;
        cursor[i] = base;
        base += deg[i];
    }
    if (t == 1023) rowptr[N] = part[1023];
}

__global__ __launch_bounds__(256) void csr_fill(const int* __restrict__ ei,
                                                int* __restrict__ cursor,
                                                int* __restrict__ csr_src,
                                                int* __restrict__ csr_eid,
                                                int E, int Etot)
{
    int i = blockIdx.x * 256 + threadIdx.x;
    if (i >= Etot) return;
    int src, dst;
    if (i < E) { src = ei[i]; dst = ei[E + i]; }
    else       { src = dst = i - E; }
    int pos = atomicAdd(&cursor[dst], 1);
    csr_src[pos] = src;
    csr_eid[pos] = i;
}

// ---------- edge pass A: logits + segment max ----------
__global__ __launch_bounds__(256) void edge_logits(const float* __restrict__ xl,
                                                   const float* __restrict__ xr,
                                                   const int* __restrict__ ei,
                                                   const float* __restrict__ att,
                                                   float* __restrict__ logit_out,
                                                   unsigned* __restrict__ lmax,
                                                   int E, int Etot)
{
    int gw = (blockIdx.x * 256 + threadIdx.x) >> 6;
    int lane = threadIdx.x & 63;
    if (gw >= Etot) return;
    int src, dst;
    if (gw < E) { src = ei[gw]; dst = ei[E + gw]; }
    else        { src = dst = gw - E; }

    const float4* xls = (const float4*)(xl + (size_t)src * FEAT) + lane * 2;
    const float4* xrs = (const float4*)(xr + (size_t)dst * FEAT) + lane * 2;
    const float4* at4 = (const float4*)att + lane * 2;
    float4 a0 = xls[0], a1 = xls[1];
    float4 b0 = xrs[0], b1 = xrs[1];
    float4 t0 = at4[0], t1 = at4[1];

    float xa[8] = {a0.x, a0.y, a0.z, a0.w, a1.x, a1.y, a1.z, a1.w};
    float xb[8] = {b0.x, b0.y, b0.z, b0.w, b1.x, b1.y, b1.z, b1.w};
    float tt[8] = {t0.x, t0.y, t0.z, t0.w, t1.x, t1.y, t1.z, t1.w};
    float s = 0.f;
    #pragma unroll
    for (int k = 0; k < 8; ++k) {
        float v = xa[k] + xb[k];
        v = (v > 0.f) ? v : NEG_SLOPE * v;
        s += v * tt[k];
    }
    #pragma unroll
    for (int off = 1; off < 16; off <<= 1) s += __shfl_xor(s, off, 64);

    if ((lane & 15) == 0) {
        int head = lane >> 4;
        logit_out[(size_t)gw * NH + head] = s;
        atomicMax(&lmax[dst * NH + head], mapf(s));
    }
}

// ---------- edge pass B: exp + segment sum ----------
__global__ __launch_bounds__(256) void edge_expsum(float* __restrict__ logit_ex,
                                                   const int* __restrict__ ei,
                                                   const unsigned* __restrict__ lmax,
                                                   float* __restrict__ denom,
                                                   int E, int Etot)
{
    int i = blockIdx.x * 256 + threadIdx.x;
    if (i >= Etot * NH) return;
    int e = i >> 2, h = i & 3;
    int dst = (e < E) ? ei[E + e] : (e - E);
    float m = unmapf(lmax[dst * NH + h]);
    float ex = expf(logit_ex[i] - m);
    logit_ex[i] = ex;
    atomicAdd(&denom[dst * NH + h], ex);
}

// ---------- edge pass C: normalize alpha in place ----------
__global__ __launch_bounds__(256) void edge_norm(float* __restrict__ alpha,
                                                 const int* __restrict__ ei,
                                                 const float* __restrict__ denom,
                                                 int E, int Etot)
{
    int i = blockIdx.x * 256 + threadIdx.x;
    if (i >= Etot * NH) return;
    int e = i >> 2, h = i & 3;
    int dst = (e < E) ? ei[E + e] : (e - E);
    alpha[i] = alpha[i] / (denom[dst * NH + h] + 1e-16f);
}

// ---------- node gather + mean heads + bias + BN + ReLU ----------
// one wave per node; lane covers 8 floats of the 512-wide row, head=lane/16
__global__ __launch_bounds__(256) void node_gather_bn(const float* __restrict__ xl,
                                                      const float* __restrict__ alpha,
                                                      const int* __restrict__ rowptr,
                                                      const int* __restrict__ csr_src,
                                                      const int* __restrict__ csr_eid,
                                                      const float* __restrict__ bias,
                                                      const float* __restrict__ g,
                                                      const float* __restrict__ be,
                                                      const float* __restrict__ m,
                                                      const float* __restrict__ v,
                                                      float* __restrict__ hout, int N)
{
    int n = (blockIdx.x * 256 + threadIdx.x) >> 6;
    int lane = threadIdx.x & 63;
    if (n >= N) return;
    int head = lane >> 4, sub = lane & 15;
    int beg = rowptr[n], end = rowptr[n + 1];
    float acc[8] = {};
    const size_t feat_off = head * HID + sub * 8;
    for (int k = beg; k < end; ++k) {
        int src = csr_src[k];
        int eid = csr_eid[k];
        float a = alpha[(size_t)eid * NH + head];
        const float4* p = (const float4*)(xl + (size_t)src * FEAT + feat_off);
        float4 v0 = p[0], v1 = p[1];
        acc[0] += a * v0.x; acc[1] += a * v0.y;
        acc[2] += a * v0.z; acc[3] += a * v0.w;
        acc[4] += a * v1.x; acc[5] += a * v1.y;
        acc[6] += a * v1.z; acc[7] += a * v1.w;
    }
    // sum the 4 heads: lanes l, l^16, l^32, l^48 hold same channels
    #pragma unroll
    for (int j = 0; j < 8; ++j) {
        acc[j] += __shfl_xor(acc[j], 16, 64);
        acc[j] += __shfl_xor(acc[j], 32, 64);
    }
    if (head == 0) {
        int c0 = sub * 8;
        #pragma unroll
        for (int j = 0; j < 8; ++j) {
            int c = c0 + j;
            float s = acc[j] * 0.25f + bias[c];
            float bn = (s - m[c]) * rsqrtf(v[c] + BN_EPS) * g[c] + be[c];
            hout[(size_t)n * HID + c] = fmaxf(bn, 0.f);
        }
    }
}

// ---------- final linear + relu + sigmoid ----------
__global__ __launch_bounds__(256) void final_lin(const float* __restrict__ h,
                                                 const float* __restrict__ W,
                                                 const float* __restrict__ b,
                                                 float* __restrict__ out, int N)
{
    int gw = (blockIdx.x * 256 + threadIdx.x) >> 6;
    int lane = threadIdx.x & 63;
    if (gw >= N) return;
    const float* hp = h + (size_t)gw * HID;
    float s = hp[lane] * W[lane] + hp[64 + lane] * W[64 + lane];
    #pragma unroll
    for (int off = 1; off < 64; off <<= 1) s += __shfl_xor(s, off, 64);
    if (lane == 0) {
        float z = fmaxf(s + b[0], 0.f);
        out[gw] = 1.f / (1.f + expf(-z));
    }
}

extern "C" void kernel_launch(void* const* d_in, const int* in_sizes, int n_in,
                              void* d_out, int out_size, void* d_ws, size_t ws_size,
                              hipStream_t stream)
{
    const float* x    = (const float*)d_in[0];
    const int*   ei   = (const int*)d_in[1];
    const float* Wl1  = (const float*)d_in[2];
    const float* Wr1  = (const float*)d_in[3];
    const float* att1 = (const float*)d_in[4];
    const float* b1   = (const float*)d_in[5];
    const float* Wl2  = (const float*)d_in[6];
    const float* Wr2  = (const float*)d_in[7];
    const float* att2 = (const float*)d_in[8];
    const float* b2   = (const float*)d_in[9];
    const float* g1   = (const float*)d_in[10];
    const float* be1  = (const float*)d_in[11];
    const float* m1   = (const float*)d_in[12];
    const float* v1   = (const float*)d_in[13];
    const float* g2   = (const float*)d_in[14];
    const float* be2  = (const float*)d_in[15];
    const float* m2   = (const float*)d_in[16];
    const float* v2   = (const float*)d_in[17];
    const float* Wlin = (const float*)d_in[18];
    const float* blin = (const float*)d_in[19];

    const int IN_C = 256;
    const int N = in_sizes[0] / IN_C;       // 10000
    const int E = in_sizes[1] / 2;          // 320000
    const int Etot = E + N;                 // with self loops

    float* out    = (float*)d_out;          // [N]
    float* alpha1 = out + N;                // [Etot*NH]
    float* alpha2 = alpha1 + (size_t)Etot * NH;

    // workspace layout
    float*    ws     = (float*)d_ws;
    unsigned* lmax   = (unsigned*)ws;                        // N*NH
    float*    denom  = ws + (size_t)N * NH;                  // N*NH
    float*    xl     = denom + (size_t)N * NH;               // N*FEAT
    float*    xr     = xl + (size_t)N * FEAT;                // N*FEAT
    float*    hbuf   = xr + (size_t)N * FEAT;                // N*HID
    int*      deg    = (int*)(hbuf + (size_t)N * HID);       // N
    int*      cursor = deg + N;                              // N
    int*      rowptr = cursor + N;                           // N+1
    int*      csrsrc = rowptr + (N + 1);                     // Etot
    int*      csreid = csrsrc + Etot;                        // Etot

    dim3 blk(256);
    dim3 gemm_grid((N + 63) / 64, FEAT / 64);
    int edge_wave_blocks = (Etot + 3) / 4;
    int eh_blocks = (Etot * NH + 255) / 256;
    int node_wave_blocks = (N + 3) / 4;
    int etot_blocks = (Etot + 255) / 256;

    const size_t softmax_zero = (size_t)N * NH * 2 * sizeof(float);

    // ---- CSR build (shared by both layers) ----
    hipMemsetAsync(deg, 0, (size_t)N * sizeof(int), stream);
    csr_count<<<etot_blocks, blk, 0, stream>>>(ei, deg, E, Etot);
    scan_rowptr<<<1, 1024, 0, stream>>>(deg, rowptr, cursor, N);
    csr_fill<<<etot_blocks, blk, 0, stream>>>(ei, cursor, csrsrc, csreid, E, Etot);

    // ================= layer 1 =================
    hipMemsetAsync(lmax, 0, softmax_zero, stream);
    gemm_f32<<<gemm_grid, blk, 0, stream>>>(x, Wl1, xl, N, FEAT, IN_C);
    gemm_f32<<<gemm_grid, blk, 0, stream>>>(x, Wr1, xr, N, FEAT, IN_C);
    edge_logits<<<edge_wave_blocks, blk, 0, stream>>>(xl, xr, ei, att1, alpha1, lmax, E, Etot);
    edge_expsum<<<eh_blocks, blk, 0, stream>>>(alpha1, ei, lmax, denom, E, Etot);
    edge_norm<<<eh_blocks, blk, 0, stream>>>(alpha1, ei, denom, E, Etot);
    node_gather_bn<<<node_wave_blocks, blk, 0, stream>>>(xl, alpha1, rowptr, csrsrc, csreid,
                                                         b1, g1, be1, m1, v1, hbuf, N);

    // ================= layer 2 =================
    hipMemsetAsync(lmax, 0, softmax_zero, stream);
    gemm_f32<<<gemm_grid, blk, 0, stream>>>(hbuf, Wl2, xl, N, FEAT, HID);
    gemm_f32<<<gemm_grid, blk, 0, stream>>>(hbuf, Wr2, xr, N, FEAT, HID);
    edge_logits<<<edge_wave_blocks, blk, 0, stream>>>(xl, xr, ei, att2, alpha2, lmax, E, Etot);
    edge_expsum<<<eh_blocks, blk, 0, stream>>>(alpha2, ei, lmax, denom, E, Etot);
    edge_norm<<<eh_blocks, blk, 0, stream>>>(alpha2, ei, denom, E, Etot);
    node_gather_bn<<<node_wave_blocks, blk, 0, stream>>>(xl, alpha2, rowptr, csrsrc, csreid,
                                                         b2, g2, be2, m2, v2, hbuf, N);

    // ================= head =================
    final_lin<<<node_wave_blocks, blk, 0, stream>>>(hbuf, Wlin, blin, out, N);
}

// Round 3
// 430.751 us; speedup vs baseline: 22.4680x; 1.7732x over previous
//
#include <hip/hip_runtime.h>
#include <hip/hip_bf16.h>

#define HID 128
#define NH  4          // heads
#define FEAT (NH*HID)  // 512 per node per projection
#define NEG_SLOPE 0.2f
#define BN_EPS 1e-5f

// ---------- f32 tiled GEMM: C[M,Nc] = A[M,K] @ B[K,Nc] ----------
__global__ __launch_bounds__(256) void gemm_f32(const float* __restrict__ A,
                                                const float* __restrict__ B,
                                                float* __restrict__ C,
                                                int M, int Nc, int K)
{
    __shared__ float As[16][64];   // transposed: As[k][row]
    __shared__ float Bs[16][64];
    const int bm = blockIdx.x * 64;
    const int bn = blockIdx.y * 64;
    const int tid = threadIdx.x;
    const int tx = tid & 15, ty = tid >> 4;
    float acc[4][4] = {};
    for (int k0 = 0; k0 < K; k0 += 16) {
        {
            int r = tid >> 2;
            int c = (tid & 3) << 2;
            int gr = bm + r;
            float4 av = make_float4(0.f, 0.f, 0.f, 0.f);
            if (gr < M) av = *(const float4*)(A + (size_t)gr * K + k0 + c);
            As[c + 0][r] = av.x; As[c + 1][r] = av.y;
            As[c + 2][r] = av.z; As[c + 3][r] = av.w;
        }
        {
            int r = tid >> 4;
            int c = (tid & 15) << 2;
            float4 bv = *(const float4*)(B + (size_t)(k0 + r) * Nc + bn + c);
            *(float4*)&Bs[r][c] = bv;
        }
        __syncthreads();
        #pragma unroll
        for (int kk = 0; kk < 16; ++kk) {
            float4 a4 = *(const float4*)&As[kk][ty << 2];
            float4 b4 = *(const float4*)&Bs[kk][tx << 2];
            float a_[4] = {a4.x, a4.y, a4.z, a4.w};
            float b_[4] = {b4.x, b4.y, b4.z, b4.w};
            #pragma unroll
            for (int i = 0; i < 4; ++i)
                #pragma unroll
                for (int j = 0; j < 4; ++j)
                    acc[i][j] += a_[i] * b_[j];
        }
        __syncthreads();
    }
    #pragma unroll
    for (int i = 0; i < 4; ++i) {
        int gr = bm + (ty << 2) + i;
        if (gr < M) {
            float4 v = make_float4(acc[i][0], acc[i][1], acc[i][2], acc[i][3]);
            *(float4*)(C + (size_t)gr * Nc + bn + (tx << 2)) = v;
        }
    }
}

// ---------- CSR build ----------
__global__ __launch_bounds__(256) void csr_count(const int* __restrict__ ei,
                                                 int* __restrict__ deg,
                                                 int E, int Etot)
{
    int i = blockIdx.x * 256 + threadIdx.x;
    if (i >= Etot) return;
    int dst = (i < E) ? ei[E + i] : (i - E);
    atomicAdd(&deg[dst], 1);
}

__global__ __launch_bounds__(1024) void scan_rowptr(const int* __restrict__ deg,
                                                    int* __restrict__ rowptr,
                                                    int* __restrict__ cursor,
                                                    int N)
{
    __shared__ int part[1024];
    int t = threadIdx.x;
    int chunk = (N + 1023) / 1024;
    int lo = t * chunk;
    int hi = lo + chunk; if (hi > N) hi = N; if (lo > N) lo = N;
    int s = 0;
    for (int i = lo; i < hi; ++i) s += deg[i];
    part[t] = s;
    __syncthreads();
    for (int off = 1; off < 1024; off <<= 1) {
        int v = (t >= off) ? part[t - off] : 0;
        __syncthreads();
        part[t] += v;
        __syncthreads();
    }
    int base = (t == 0) ? 0 : part[t - 1];
    for (int i = lo; i < hi; ++i) {
        rowptr[i] = base;
        cursor[i] = base;
        base += deg[i];
    }
    if (t == 1023) rowptr[N] = part[1023];
}

__global__ __launch_bounds__(256) void csr_fill(const int* __restrict__ ei,
                                                int* __restrict__ cursor,
                                                int* __restrict__ csr_src,
                                                int* __restrict__ csr_eid,
                                                int E, int Etot)
{
    int i = blockIdx.x * 256 + threadIdx.x;
    if (i >= Etot) return;
    int src, dst;
    if (i < E) { src = ei[i]; dst = ei[E + i]; }
    else       { src = dst = i - E; }
    int pos = atomicAdd(&cursor[dst], 1);
    csr_src[pos] = src;
    csr_eid[pos] = i;
}

// ---------- fused per-dst attention: logits + online softmax + weighted
// gather + head-mean + bias + BN + ReLU.
// One wave per dst node. lane: head = lane>>4, sub = lane&15 covers 8 channels.
// Writes raw logits into alpha (finalized by alpha_finalize) and (m,den) to msum.
__global__ __launch_bounds__(256) void fused_attn(const float* __restrict__ xl,
                                                  const float* __restrict__ xr,
                                                  const int* __restrict__ rowptr,
                                                  const int* __restrict__ csr_src,
                                                  const int* __restrict__ csr_eid,
                                                  const float* __restrict__ att,
                                                  float* __restrict__ alpha_raw,
                                                  float* __restrict__ msum,   // [2*N*NH]
                                                  const float* __restrict__ bias,
                                                  const float* __restrict__ g,
                                                  const float* __restrict__ be,
                                                  const float* __restrict__ bm,
                                                  const float* __restrict__ bv,
                                                  float* __restrict__ hout, int N)
{
    int n = (blockIdx.x * 256 + threadIdx.x) >> 6;
    int lane = threadIdx.x & 63;
    if (n >= N) return;
    int head = lane >> 4, sub = lane & 15;
    const size_t foff = (size_t)head * HID + sub * 8;

    float xrv[8], atv[8];
    {
        const float4* p = (const float4*)(xr + (size_t)n * FEAT + foff);
        float4 r0 = p[0], r1 = p[1];
        xrv[0]=r0.x; xrv[1]=r0.y; xrv[2]=r0.z; xrv[3]=r0.w;
        xrv[4]=r1.x; xrv[5]=r1.y; xrv[6]=r1.z; xrv[7]=r1.w;
        const float4* a4 = (const float4*)(att + foff);
        float4 t0 = a4[0], t1 = a4[1];
        atv[0]=t0.x; atv[1]=t0.y; atv[2]=t0.z; atv[3]=t0.w;
        atv[4]=t1.x; atv[5]=t1.y; atv[6]=t1.z; atv[7]=t1.w;
    }

    float mrun = -1e30f, den = 0.f, acc[8] = {};
    int beg = rowptr[n], end = rowptr[n + 1];
    for (int k = beg; k < end; ++k) {
        int src = csr_src[k];
        int eid = csr_eid[k];
        const float4* p = (const float4*)(xl + (size_t)src * FEAT + foff);
        float4 v0 = p[0], v1 = p[1];
        float xv[8] = {v0.x, v0.y, v0.z, v0.w, v1.x, v1.y, v1.z, v1.w};
        float s = 0.f;
        #pragma unroll
        for (int j = 0; j < 8; ++j) {
            float t = xv[j] + xrv[j];
            t = (t > 0.f) ? t : NEG_SLOPE * t;
            s += t * atv[j];
        }
        s += __shfl_xor(s, 1, 64);
        s += __shfl_xor(s, 2, 64);
        s += __shfl_xor(s, 4, 64);
        s += __shfl_xor(s, 8, 64);
        if (sub == 0) alpha_raw[(size_t)eid * NH + head] = s;
        if (s > mrun) {
            float sc = expf(mrun - s);
            den *= sc;
            #pragma unroll
            for (int j = 0; j < 8; ++j) acc[j] *= sc;
            mrun = s;
        }
        float e = expf(s - mrun);
        den += e;
        #pragma unroll
        for (int j = 0; j < 8; ++j) acc[j] += e * xv[j];
    }
    if (sub == 0) {
        msum[n * NH + head] = mrun;
        msum[(size_t)N * NH + n * NH + head] = den;
    }
    float inv = 1.f / (den + 1e-16f);
    float t8[8];
    #pragma unroll
    for (int j = 0; j < 8; ++j) {
        float t = acc[j] * inv;
        t += __shfl_xor(t, 16, 64);
        t += __shfl_xor(t, 32, 64);
        t8[j] = t;
    }
    if (head == 0) {
        float o[8];
        #pragma unroll
        for (int j = 0; j < 8; ++j) {
            int c = sub * 8 + j;
            float s = t8[j] * 0.25f + bias[c];
            float bn = (s - bm[c]) * rsqrtf(bv[c] + BN_EPS) * g[c] + be[c];
            o[j] = fmaxf(bn, 0.f);
        }
        float* hp = hout + (size_t)n * HID + sub * 8;
        *(float4*)(hp + 0) = make_float4(o[0], o[1], o[2], o[3]);
        *(float4*)(hp + 4) = make_float4(o[4], o[5], o[6], o[7]);
    }
}

// ---------- finalize alpha: exp(logit - m[dst]) / den[dst] ----------
__global__ __launch_bounds__(256) void alpha_finalize(float* __restrict__ alpha,
                                                      const int* __restrict__ ei,
                                                      const float* __restrict__ msum,
                                                      int N, int E, int Etot)
{
    int i = blockIdx.x * 256 + threadIdx.x;
    if (i >= Etot * NH) return;
    int e = i >> 2, h = i & 3;
    int dst = (e < E) ? ei[E + e] : (e - E);
    float m = msum[dst * NH + h];
    float den = msum[(size_t)N * NH + dst * NH + h];
    alpha[i] = expf(alpha[i] - m) / (den + 1e-16f);
}

// ---------- final linear + relu + sigmoid ----------
__global__ __launch_bounds__(256) void final_lin(const float* __restrict__ h,
                                                 const float* __restrict__ W,
                                                 const float* __restrict__ b,
                                                 float* __restrict__ out, int N)
{
    int gw = (blockIdx.x * 256 + threadIdx.x) >> 6;
    int lane = threadIdx.x & 63;
    if (gw >= N) return;
    const float* hp = h + (size_t)gw * HID;
    float s = hp[lane] * W[lane] + hp[64 + lane] * W[64 + lane];
    #pragma unroll
    for (int off = 1; off < 64; off <<= 1) s += __shfl_xor(s, off, 64);
    if (lane == 0) {
        float z = fmaxf(s + b[0], 0.f);
        out[gw] = 1.f / (1.f + expf(-z));
    }
}

extern "C" void kernel_launch(void* const* d_in, const int* in_sizes, int n_in,
                              void* d_out, int out_size, void* d_ws, size_t ws_size,
                              hipStream_t stream)
{
    const float* x    = (const float*)d_in[0];
    const int*   ei   = (const int*)d_in[1];
    const float* Wl1  = (const float*)d_in[2];
    const float* Wr1  = (const float*)d_in[3];
    const float* att1 = (const float*)d_in[4];
    const float* b1   = (const float*)d_in[5];
    const float* Wl2  = (const float*)d_in[6];
    const float* Wr2  = (const float*)d_in[7];
    const float* att2 = (const float*)d_in[8];
    const float* b2   = (const float*)d_in[9];
    const float* g1   = (const float*)d_in[10];
    const float* be1  = (const float*)d_in[11];
    const float* m1   = (const float*)d_in[12];
    const float* v1   = (const float*)d_in[13];
    const float* g2   = (const float*)d_in[14];
    const float* be2  = (const float*)d_in[15];
    const float* m2   = (const float*)d_in[16];
    const float* v2   = (const float*)d_in[17];
    const float* Wlin = (const float*)d_in[18];
    const float* blin = (const float*)d_in[19];

    const int IN_C = 256;
    const int N = in_sizes[0] / IN_C;       // 10000
    const int E = in_sizes[1] / 2;          // 320000
    const int Etot = E + N;                 // with self loops

    float* out    = (float*)d_out;          // [N]
    float* alpha1 = out + N;                // [Etot*NH]
    float* alpha2 = alpha1 + (size_t)Etot * NH;

    // workspace layout
    float*    ws     = (float*)d_ws;
    float*    msum   = ws;                                   // 2*N*NH (m, den)
    float*    xl     = msum + (size_t)N * NH * 2;            // N*FEAT
    float*    xr     = xl + (size_t)N * FEAT;                // N*FEAT
    float*    hbuf   = xr + (size_t)N * FEAT;                // N*HID
    int*      deg    = (int*)(hbuf + (size_t)N * HID);       // N
    int*      cursor = deg + N;                              // N
    int*      rowptr = cursor + N;                           // N+1
    int*      csrsrc = rowptr + (N + 1);                     // Etot
    int*      csreid = csrsrc + Etot;                        // Etot

    dim3 blk(256);
    dim3 gemm_grid((N + 63) / 64, FEAT / 64);
    int eh_blocks = (Etot * NH + 255) / 256;
    int node_wave_blocks = (N + 3) / 4;
    int etot_blocks = (Etot + 255) / 256;

    // ---- CSR build (shared by both layers) ----
    hipMemsetAsync(deg, 0, (size_t)N * sizeof(int), stream);
    csr_count<<<etot_blocks, blk, 0, stream>>>(ei, deg, E, Etot);
    scan_rowptr<<<1, 1024, 0, stream>>>(deg, rowptr, cursor, N);
    csr_fill<<<etot_blocks, blk, 0, stream>>>(ei, cursor, csrsrc, csreid, E, Etot);

    // ================= layer 1 =================
    gemm_f32<<<gemm_grid, blk, 0, stream>>>(x, Wl1, xl, N, FEAT, IN_C);
    gemm_f32<<<gemm_grid, blk, 0, stream>>>(x, Wr1, xr, N, FEAT, IN_C);
    fused_attn<<<node_wave_blocks, blk, 0, stream>>>(xl, xr, rowptr, csrsrc, csreid,
                                                     att1, alpha1, msum,
                                                     b1, g1, be1, m1, v1, hbuf, N);
    alpha_finalize<<<eh_blocks, blk, 0, stream>>>(alpha1, ei, msum, N, E, Etot);

    // ================= layer 2 =================
    gemm_f32<<<gemm_grid, blk, 0, stream>>>(hbuf, Wl2, xl, N, FEAT, HID);
    gemm_f32<<<gemm_grid, blk, 0, stream>>>(hbuf, Wr2, xr, N, FEAT, HID);
    fused_attn<<<node_wave_blocks, blk, 0, stream>>>(xl, xr, rowptr, csrsrc, csreid,
                                                     att2, alpha2, msum,
                                                     b2, g2, be2, m2, v2, hbuf, N);
    alpha_finalize<<<eh_blocks, blk, 0, stream>>>(alpha2, ei, msum, N, E, Etot);

    // ================= head =================
    final_lin<<<node_wave_blocks, blk, 0, stream>>>(hbuf, Wlin, blin, out, N);
}

// Round 4
// 401.797 us; speedup vs baseline: 24.0870x; 1.0721x over previous
//
#include <hip/hip_runtime.h>
#include <hip/hip_bf16.h>

#define HID 128
#define NH  4          // heads
#define FEAT (NH*HID)  // 512 per node per projection
#define NEG_SLOPE 0.2f
#define BN_EPS 1e-5f

// ---------- f32 tiled GEMM: C[M,Nc] = A[M,K] @ B[K,Nc] ----------
// 128x64 tile, BK=16, 256 threads, 8x4 microtile. K%16==0, Nc%64==0.
__global__ __launch_bounds__(256) void gemm_f32(const float* __restrict__ A,
                                                const float* __restrict__ B,
                                                float* __restrict__ C,
                                                int M, int Nc, int K)
{
    __shared__ float As[16][129];  // transposed: As[k][row], pad row-dim
    __shared__ float Bs[16][68];
    const int bm = blockIdx.x * 128;
    const int bn = blockIdx.y * 64;
    const int tid = threadIdx.x;
    const int tx = tid & 15, ty = tid >> 4;   // tx: 16 col-groups, ty: 16 row-groups
    float acc[8][4] = {};
    const int ra = tid >> 2;            // 0..63
    const int ca = (tid & 3) << 2;      // 0,4,8,12
    const int rb = tid >> 4;            // 0..15
    const int cb = (tid & 15) << 2;     // 0..60
    for (int k0 = 0; k0 < K; k0 += 16) {
        {
            float4 a0 = make_float4(0.f, 0.f, 0.f, 0.f);
            float4 a1 = make_float4(0.f, 0.f, 0.f, 0.f);
            if (bm + ra < M)      a0 = *(const float4*)(A + (size_t)(bm + ra) * K + k0 + ca);
            if (bm + ra + 64 < M) a1 = *(const float4*)(A + (size_t)(bm + ra + 64) * K + k0 + ca);
            As[ca + 0][ra] = a0.x; As[ca + 1][ra] = a0.y;
            As[ca + 2][ra] = a0.z; As[ca + 3][ra] = a0.w;
            As[ca + 0][ra + 64] = a1.x; As[ca + 1][ra + 64] = a1.y;
            As[ca + 2][ra + 64] = a1.z; As[ca + 3][ra + 64] = a1.w;
            float4 bv = *(const float4*)(B + (size_t)(k0 + rb) * Nc + bn + cb);
            *(float4*)&Bs[rb][cb] = bv;
        }
        __syncthreads();
        #pragma unroll
        for (int kk = 0; kk < 16; ++kk) {
            float4 b4 = *(const float4*)&Bs[kk][tx << 2];
            float4 al = *(const float4*)&As[kk][ty << 3];
            float4 ah = *(const float4*)&As[kk][(ty << 3) + 4];
            float a_[8] = {al.x, al.y, al.z, al.w, ah.x, ah.y, ah.z, ah.w};
            float b_[4] = {b4.x, b4.y, b4.z, b4.w};
            #pragma unroll
            for (int i = 0; i < 8; ++i)
                #pragma unroll
                for (int j = 0; j < 4; ++j)
                    acc[i][j] += a_[i] * b_[j];
        }
        __syncthreads();
    }
    #pragma unroll
    for (int i = 0; i < 8; ++i) {
        int gr = bm + (ty << 3) + i;
        if (gr < M) {
            float4 v = make_float4(acc[i][0], acc[i][1], acc[i][2], acc[i][3]);
            *(float4*)(C + (size_t)gr * Nc + bn + (tx << 2)) = v;
        }
    }
}

// ---------- CSR build ----------
__global__ __launch_bounds__(256) void csr_count(const int* __restrict__ ei,
                                                 int* __restrict__ deg,
                                                 int E, int Etot)
{
    int i = blockIdx.x * 256 + threadIdx.x;
    if (i >= Etot) return;
    int dst = (i < E) ? ei[E + i] : (i - E);
    atomicAdd(&deg[dst], 1);
}

__global__ __launch_bounds__(1024) void scan_rowptr(const int* __restrict__ deg,
                                                    int* __restrict__ rowptr,
                                                    int* __restrict__ cursor,
                                                    int N)
{
    __shared__ int part[1024];
    int t = threadIdx.x;
    int chunk = (N + 1023) / 1024;
    int lo = t * chunk;
    int hi = lo + chunk; if (hi > N) hi = N; if (lo > N) lo = N;
    int s = 0;
    for (int i = lo; i < hi; ++i) s += deg[i];
    part[t] = s;
    __syncthreads();
    for (int off = 1; off < 1024; off <<= 1) {
        int v = (t >= off) ? part[t - off] : 0;
        __syncthreads();
        part[t] += v;
        __syncthreads();
    }
    int base = (t == 0) ? 0 : part[t - 1];
    for (int i = lo; i < hi; ++i) {
        rowptr[i] = base;
        cursor[i] = base;
        base += deg[i];
    }
    if (t == 1023) rowptr[N] = part[1023];
}

__global__ __launch_bounds__(256) void csr_fill(const int* __restrict__ ei,
                                                int* __restrict__ cursor,
                                                int* __restrict__ csr_src,
                                                int* __restrict__ csr_eid,
                                                int E, int Etot)
{
    int i = blockIdx.x * 256 + threadIdx.x;
    if (i >= Etot) return;
    int src, dst;
    if (i < E) { src = ei[i]; dst = ei[E + i]; }
    else       { src = dst = i - E; }
    int pos = atomicAdd(&cursor[dst], 1);
    csr_src[pos] = src;
    csr_eid[pos] = i;
}

// ---------- fused per-dst attention, unroll-4 online softmax ----------
__global__ __launch_bounds__(256) void fused_attn(const float* __restrict__ xl,
                                                  const float* __restrict__ xr,
                                                  const int* __restrict__ rowptr,
                                                  const int* __restrict__ csr_src,
                                                  const int* __restrict__ csr_eid,
                                                  const float* __restrict__ att,
                                                  float* __restrict__ alpha_raw,
                                                  float* __restrict__ msum,   // [2*N*NH]
                                                  const float* __restrict__ bias,
                                                  const float* __restrict__ g,
                                                  const float* __restrict__ be,
                                                  const float* __restrict__ bm,
                                                  const float* __restrict__ bv,
                                                  float* __restrict__ hout, int N)
{
    int n = (blockIdx.x * 256 + threadIdx.x) >> 6;
    int lane = threadIdx.x & 63;
    if (n >= N) return;
    int head = lane >> 4, sub = lane & 15;
    const size_t foff = (size_t)head * HID + sub * 8;

    float xrv[8], atv[8];
    {
        const float4* p = (const float4*)(xr + (size_t)n * FEAT + foff);
        float4 r0 = p[0], r1 = p[1];
        xrv[0]=r0.x; xrv[1]=r0.y; xrv[2]=r0.z; xrv[3]=r0.w;
        xrv[4]=r1.x; xrv[5]=r1.y; xrv[6]=r1.z; xrv[7]=r1.w;
        const float4* a4 = (const float4*)(att + foff);
        float4 t0 = a4[0], t1 = a4[1];
        atv[0]=t0.x; atv[1]=t0.y; atv[2]=t0.z; atv[3]=t0.w;
        atv[4]=t1.x; atv[5]=t1.y; atv[6]=t1.z; atv[7]=t1.w;
    }

    float mrun = -1e30f, den = 0.f, acc[8] = {};
    int beg = rowptr[n], end = rowptr[n + 1];
    int k = beg;

    for (; k + 3 < end; k += 4) {
        int s0 = csr_src[k],     s1 = csr_src[k + 1];
        int s2 = csr_src[k + 2], s3 = csr_src[k + 3];
        int e0 = csr_eid[k],     e1 = csr_eid[k + 1];
        int e2 = csr_eid[k + 2], e3 = csr_eid[k + 3];

        const float4* p0 = (const float4*)(xl + (size_t)s0 * FEAT + foff);
        const float4* p1 = (const float4*)(xl + (size_t)s1 * FEAT + foff);
        const float4* p2 = (const float4*)(xl + (size_t)s2 * FEAT + foff);
        const float4* p3 = (const float4*)(xl + (size_t)s3 * FEAT + foff);
        float4 a0 = p0[0], b0 = p0[1];
        float4 a1 = p1[0], b1 = p1[1];
        float4 a2 = p2[0], b2 = p2[1];
        float4 a3 = p3[0], b3 = p3[1];
        float xv0[8] = {a0.x,a0.y,a0.z,a0.w,b0.x,b0.y,b0.z,b0.w};
        float xv1[8] = {a1.x,a1.y,a1.z,a1.w,b1.x,b1.y,b1.z,b1.w};
        float xv2[8] = {a2.x,a2.y,a2.z,a2.w,b2.x,b2.y,b2.z,b2.w};
        float xv3[8] = {a3.x,a3.y,a3.z,a3.w,b3.x,b3.y,b3.z,b3.w};

        float l0 = 0.f, l1 = 0.f, l2 = 0.f, l3 = 0.f;
        #pragma unroll
        for (int j = 0; j < 8; ++j) {
            float t0 = xv0[j] + xrv[j]; t0 = (t0 > 0.f) ? t0 : NEG_SLOPE * t0;
            float t1 = xv1[j] + xrv[j]; t1 = (t1 > 0.f) ? t1 : NEG_SLOPE * t1;
            float t2 = xv2[j] + xrv[j]; t2 = (t2 > 0.f) ? t2 : NEG_SLOPE * t2;
            float t3 = xv3[j] + xrv[j]; t3 = (t3 > 0.f) ? t3 : NEG_SLOPE * t3;
            l0 += t0 * atv[j]; l1 += t1 * atv[j];
            l2 += t2 * atv[j]; l3 += t3 * atv[j];
        }
        #pragma unroll
        for (int off = 1; off < 16; off <<= 1) {
            l0 += __shfl_xor(l0, off, 64);
            l1 += __shfl_xor(l1, off, 64);
            l2 += __shfl_xor(l2, off, 64);
            l3 += __shfl_xor(l3, off, 64);
        }
        if (sub == 0) {
            alpha_raw[(size_t)e0 * NH + head] = l0;
            alpha_raw[(size_t)e1 * NH + head] = l1;
            alpha_raw[(size_t)e2 * NH + head] = l2;
            alpha_raw[(size_t)e3 * NH + head] = l3;
        }
        float bmax = fmaxf(fmaxf(l0, l1), fmaxf(l2, l3));
        if (bmax > mrun) {
            float sc = __expf(mrun - bmax);
            den *= sc;
            #pragma unroll
            for (int j = 0; j < 8; ++j) acc[j] *= sc;
            mrun = bmax;
        }
        float w0 = __expf(l0 - mrun), w1 = __expf(l1 - mrun);
        float w2 = __expf(l2 - mrun), w3 = __expf(l3 - mrun);
        den += (w0 + w1) + (w2 + w3);
        #pragma unroll
        for (int j = 0; j < 8; ++j)
            acc[j] += (w0 * xv0[j] + w1 * xv1[j]) + (w2 * xv2[j] + w3 * xv3[j]);
    }

    for (; k < end; ++k) {
        int src = csr_src[k];
        int eid = csr_eid[k];
        const float4* p = (const float4*)(xl + (size_t)src * FEAT + foff);
        float4 v0 = p[0], v1 = p[1];
        float xv[8] = {v0.x, v0.y, v0.z, v0.w, v1.x, v1.y, v1.z, v1.w};
        float s = 0.f;
        #pragma unroll
        for (int j = 0; j < 8; ++j) {
            float t = xv[j] + xrv[j];
            t = (t > 0.f) ? t : NEG_SLOPE * t;
            s += t * atv[j];
        }
        #pragma unroll
        for (int off = 1; off < 16; off <<= 1) s += __shfl_xor(s, off, 64);
        if (sub == 0) alpha_raw[(size_t)eid * NH + head] = s;
        if (s > mrun) {
            float sc = __expf(mrun - s);
            den *= sc;
            #pragma unroll
            for (int j = 0; j < 8; ++j) acc[j] *= sc;
            mrun = s;
        }
        float e = __expf(s - mrun);
        den += e;
        #pragma unroll
        for (int j = 0; j < 8; ++j) acc[j] += e * xv[j];
    }

    if (sub == 0) {
        msum[n * NH + head] = mrun;
        msum[(size_t)N * NH + n * NH + head] = den;
    }
    float inv = 1.f / (den + 1e-16f);
    float t8[8];
    #pragma unroll
    for (int j = 0; j < 8; ++j) {
        float t = acc[j] * inv;
        t += __shfl_xor(t, 16, 64);
        t += __shfl_xor(t, 32, 64);
        t8[j] = t;
    }
    if (head == 0) {
        float o[8];
        #pragma unroll
        for (int j = 0; j < 8; ++j) {
            int c = sub * 8 + j;
            float s = t8[j] * 0.25f + bias[c];
            float bn = (s - bm[c]) * rsqrtf(bv[c] + BN_EPS) * g[c] + be[c];
            o[j] = fmaxf(bn, 0.f);
        }
        float* hp = hout + (size_t)n * HID + sub * 8;
        *(float4*)(hp + 0) = make_float4(o[0], o[1], o[2], o[3]);
        *(float4*)(hp + 4) = make_float4(o[4], o[5], o[6], o[7]);
    }
}

// ---------- finalize alpha: exp(logit - m[dst]) / den[dst] ----------
__global__ __launch_bounds__(256) void alpha_finalize(float* __restrict__ alpha,
                                                      const int* __restrict__ ei,
                                                      const float* __restrict__ msum,
                                                      int N, int E, int Etot)
{
    int i = blockIdx.x * 256 + threadIdx.x;
    if (i >= Etot * NH) return;
    int e = i >> 2, h = i & 3;
    int dst = (e < E) ? ei[E + e] : (e - E);
    float m = msum[dst * NH + h];
    float den = msum[(size_t)N * NH + dst * NH + h];
    alpha[i] = __expf(alpha[i] - m) / (den + 1e-16f);
}

// ---------- final linear + relu + sigmoid ----------
__global__ __launch_bounds__(256) void final_lin(const float* __restrict__ h,
                                                 const float* __restrict__ W,
                                                 const float* __restrict__ b,
                                                 float* __restrict__ out, int N)
{
    int gw = (blockIdx.x * 256 + threadIdx.x) >> 6;
    int lane = threadIdx.x & 63;
    if (gw >= N) return;
    const float* hp = h + (size_t)gw * HID;
    float s = hp[lane] * W[lane] + hp[64 + lane] * W[64 + lane];
    #pragma unroll
    for (int off = 1; off < 64; off <<= 1) s += __shfl_xor(s, off, 64);
    if (lane == 0) {
        float z = fmaxf(s + b[0], 0.f);
        out[gw] = 1.f / (1.f + expf(-z));
    }
}

extern "C" void kernel_launch(void* const* d_in, const int* in_sizes, int n_in,
                              void* d_out, int out_size, void* d_ws, size_t ws_size,
                              hipStream_t stream)
{
    const float* x    = (const float*)d_in[0];
    const int*   ei   = (const int*)d_in[1];
    const float* Wl1  = (const float*)d_in[2];
    const float* Wr1  = (const float*)d_in[3];
    const float* att1 = (const float*)d_in[4];
    const float* b1   = (const float*)d_in[5];
    const float* Wl2  = (const float*)d_in[6];
    const float* Wr2  = (const float*)d_in[7];
    const float* att2 = (const float*)d_in[8];
    const float* b2   = (const float*)d_in[9];
    const float* g1   = (const float*)d_in[10];
    const float* be1  = (const float*)d_in[11];
    const float* m1   = (const float*)d_in[12];
    const float* v1   = (const float*)d_in[13];
    const float* g2   = (const float*)d_in[14];
    const float* be2  = (const float*)d_in[15];
    const float* m2   = (const float*)d_in[16];
    const float* v2   = (const float*)d_in[17];
    const float* Wlin = (const float*)d_in[18];
    const float* blin = (const float*)d_in[19];

    const int IN_C = 256;
    const int N = in_sizes[0] / IN_C;       // 10000
    const int E = in_sizes[1] / 2;          // 320000
    const int Etot = E + N;                 // with self loops

    float* out    = (float*)d_out;          // [N]
    float* alpha1 = out + N;                // [Etot*NH]
    float* alpha2 = alpha1 + (size_t)Etot * NH;

    // workspace layout
    float*    ws     = (float*)d_ws;
    float*    msum   = ws;                                   // 2*N*NH (m, den)
    float*    xl     = msum + (size_t)N * NH * 2;            // N*FEAT
    float*    xr     = xl + (size_t)N * FEAT;                // N*FEAT
    float*    hbuf   = xr + (size_t)N * FEAT;                // N*HID
    int*      deg    = (int*)(hbuf + (size_t)N * HID);       // N
    int*      cursor = deg + N;                              // N
    int*      rowptr = cursor + N;                           // N+1
    int*      csrsrc = rowptr + (N + 1);                     // Etot
    int*      csreid = csrsrc + Etot;                        // Etot

    dim3 blk(256);
    dim3 gemm_grid((N + 127) / 128, FEAT / 64);
    int eh_blocks = (Etot * NH + 255) / 256;
    int node_wave_blocks = (N + 3) / 4;
    int etot_blocks = (Etot + 255) / 256;

    // ---- CSR build (shared by both layers) ----
    hipMemsetAsync(deg, 0, (size_t)N * sizeof(int), stream);
    csr_count<<<etot_blocks, blk, 0, stream>>>(ei, deg, E, Etot);
    scan_rowptr<<<1, 1024, 0, stream>>>(deg, rowptr, cursor, N);
    csr_fill<<<etot_blocks, blk, 0, stream>>>(ei, cursor, csrsrc, csreid, E, Etot);

    // ================= layer 1 =================
    gemm_f32<<<gemm_grid, blk, 0, stream>>>(x, Wl1, xl, N, FEAT, IN_C);
    gemm_f32<<<gemm_grid, blk, 0, stream>>>(x, Wr1, xr, N, FEAT, IN_C);
    fused_attn<<<node_wave_blocks, blk, 0, stream>>>(xl, xr, rowptr, csrsrc, csreid,
                                                     att1, alpha1, msum,
                                                     b1, g1, be1, m1, v1, hbuf, N);
    alpha_finalize<<<eh_blocks, blk, 0, stream>>>(alpha1, ei, msum, N, E, Etot);

    // ================= layer 2 =================
    gemm_f32<<<gemm_grid, blk, 0, stream>>>(hbuf, Wl2, xl, N, FEAT, HID);
    gemm_f32<<<gemm_grid, blk, 0, stream>>>(hbuf, Wr2, xr, N, FEAT, HID);
    fused_attn<<<node_wave_blocks, blk, 0, stream>>>(xl, xr, rowptr, csrsrc, csreid,
                                                     att2, alpha2, msum,
                                                     b2, g2, be2, m2, v2, hbuf, N);
    alpha_finalize<<<eh_blocks, blk, 0, stream>>>(alpha2, ei, msum, N, E, Etot);

    // ================= head =================
    final_lin<<<node_wave_blocks, blk, 0, stream>>>(hbuf, Wlin, blin, out, N);
}

// Round 5
// 271.795 us; speedup vs baseline: 35.6082x; 1.4783x over previous
//
#include <hip/hip_runtime.h>
#include <hip/hip_bf16.h>

#define HID 128
#define NH  4          // heads
#define FEAT (NH*HID)  // 512 per node per projection
#define NEG_SLOPE 0.2f
#define BN_EPS 1e-5f

typedef __attribute__((ext_vector_type(8))) short bf16x8;   // 8 bf16 = 4 VGPR
typedef __attribute__((ext_vector_type(4))) float f32x4;

// ---------- helpers ----------
__device__ inline ushort f2bf(float f) {     // RNE f32 -> bf16
    unsigned u = __float_as_uint(f);
    return (ushort)((u + 0x7fffu + ((u >> 16) & 1u)) >> 16);
}
__device__ inline void ubf8(const ushort* p, float* o) {  // 8 bf16 -> 8 f32
    uint4 q = *(const uint4*)p;
    o[0] = __uint_as_float(q.x << 16); o[1] = __uint_as_float(q.x & 0xffff0000u);
    o[2] = __uint_as_float(q.y << 16); o[3] = __uint_as_float(q.y & 0xffff0000u);
    o[4] = __uint_as_float(q.z << 16); o[5] = __uint_as_float(q.z & 0xffff0000u);
    o[6] = __uint_as_float(q.w << 16); o[7] = __uint_as_float(q.w & 0xffff0000u);
}

// ---------- cast f32 -> bf16 (n % 4 == 0) ----------
__global__ __launch_bounds__(256) void cast_bf16(const float* __restrict__ in,
                                                 ushort* __restrict__ out, int n)
{
    int i = (blockIdx.x * 256 + threadIdx.x) * 4;
    if (i >= n) return;
    float4 v = *(const float4*)(in + i);
    ushort4 o = make_ushort4(f2bf(v.x), f2bf(v.y), f2bf(v.z), f2bf(v.w));
    *(ushort4*)(out + i) = o;
}

// ---------- transpose + cast: in[K][Nc] f32 -> out[Nc][K] bf16 (K,Nc %32==0) ----------
__global__ __launch_bounds__(256) void transpose_cast(const float* __restrict__ in,
                                                      ushort* __restrict__ out,
                                                      int K, int Nc)
{
    __shared__ float t[32][33];
    int bk = blockIdx.x * 32, bc = blockIdx.y * 32;
    int r = threadIdx.x >> 3, c4 = (threadIdx.x & 7) * 4;
    float4 v = *(const float4*)(in + (size_t)(bk + r) * Nc + bc + c4);
    t[r][c4 + 0] = v.x; t[r][c4 + 1] = v.y; t[r][c4 + 2] = v.z; t[r][c4 + 3] = v.w;
    __syncthreads();
    ushort4 o;
    o.x = f2bf(t[c4 + 0][r]); o.y = f2bf(t[c4 + 1][r]);
    o.z = f2bf(t[c4 + 2][r]); o.w = f2bf(t[c4 + 3][r]);
    *(ushort4*)(out + (size_t)(bc + r) * K + bk + c4) = o;
}

// ---------- bf16 MFMA GEMM: C[M][Nc] = A[M][K] @ Bt[Nc][K]^T, all bf16 ----------
// 128x64 tile, BK=32, 256 threads = 4 waves in 2x2; per wave 4x2 frags of 16x16.
__global__ __launch_bounds__(256) void gemm_bf16(const ushort* __restrict__ A,
                                                 const ushort* __restrict__ Bt,
                                                 ushort* __restrict__ C,
                                                 int M, int Nc, int K)
{
    __shared__ __align__(16) ushort As[128 * 40];  // row stride 40 (pad 8)
    __shared__ __align__(16) ushort Bs[64 * 40];
    const int bm = blockIdx.x * 128;
    const int bn = blockIdx.y * 64;
    const int tid = threadIdx.x;
    const int wid = tid >> 6, lane = tid & 63;
    const int wr = wid >> 1, wc = wid & 1;
    const int l15 = lane & 15, l4 = lane >> 4;

    f32x4 acc[4][2] = {};

    for (int k0 = 0; k0 < K; k0 += 32) {
        #pragma unroll
        for (int s = 0; s < 2; ++s) {               // A: 512 chunks of 16B
            int c = tid + s * 256;
            int r = c >> 2, cc = (c & 3) * 8;
            uint4 v = make_uint4(0, 0, 0, 0);
            int gr = bm + r;
            if (gr < M) v = *(const uint4*)(A + (size_t)gr * K + k0 + cc);
            *(uint4*)&As[r * 40 + cc] = v;
        }
        {                                           // B: 256 chunks of 16B
            int r = tid >> 2, cc = (tid & 3) * 8;
            uint4 v = *(const uint4*)(Bt + (size_t)(bn + r) * K + k0 + cc);
            *(uint4*)&Bs[r * 40 + cc] = v;
        }
        __syncthreads();
        bf16x8 bfr[2];
        #pragma unroll
        for (int n = 0; n < 2; ++n)
            bfr[n] = *(const bf16x8*)&Bs[(wc * 32 + n * 16 + l15) * 40 + l4 * 8];
        #pragma unroll
        for (int m = 0; m < 4; ++m) {
            bf16x8 afr = *(const bf16x8*)&As[(wr * 64 + m * 16 + l15) * 40 + l4 * 8];
            #pragma unroll
            for (int n = 0; n < 2; ++n)
                acc[m][n] = __builtin_amdgcn_mfma_f32_16x16x32_bf16(afr, bfr[n], acc[m][n], 0, 0, 0);
        }
        __syncthreads();
    }
    #pragma unroll
    for (int m = 0; m < 4; ++m)
        #pragma unroll
        for (int n = 0; n < 2; ++n)
            #pragma unroll
            for (int r = 0; r < 4; ++r) {
                int row = bm + wr * 64 + m * 16 + l4 * 4 + r;
                int col = bn + wc * 32 + n * 16 + l15;
                if (row < M) C[(size_t)row * Nc + col] = f2bf(acc[m][n][r]);
            }
}

// ---------- CSR build ----------
__global__ __launch_bounds__(256) void csr_count(const int* __restrict__ ei,
                                                 int* __restrict__ deg,
                                                 int E, int Etot)
{
    int i = blockIdx.x * 256 + threadIdx.x;
    if (i >= Etot) return;
    int dst = (i < E) ? ei[E + i] : (i - E);
    atomicAdd(&deg[dst], 1);
}

__global__ __launch_bounds__(1024) void scan_rowptr(const int* __restrict__ deg,
                                                    int* __restrict__ rowptr,
                                                    int* __restrict__ cursor,
                                                    int N)
{
    __shared__ int part[1024];
    int t = threadIdx.x;
    int chunk = (N + 1023) / 1024;
    int lo = t * chunk;
    int hi = lo + chunk; if (hi > N) hi = N; if (lo > N) lo = N;
    int s = 0;
    for (int i = lo; i < hi; ++i) s += deg[i];
    part[t] = s;
    __syncthreads();
    for (int off = 1; off < 1024; off <<= 1) {
        int v = (t >= off) ? part[t - off] : 0;
        __syncthreads();
        part[t] += v;
        __syncthreads();
    }
    int base = (t == 0) ? 0 : part[t - 1];
    for (int i = lo; i < hi; ++i) {
        rowptr[i] = base;
        cursor[i] = base;
        base += deg[i];
    }
    if (t == 1023) rowptr[N] = part[1023];
}

__global__ __launch_bounds__(256) void csr_fill(const int* __restrict__ ei,
                                                int* __restrict__ cursor,
                                                int* __restrict__ csr_src,
                                                int* __restrict__ csr_eid,
                                                int E, int Etot)
{
    int i = blockIdx.x * 256 + threadIdx.x;
    if (i >= Etot) return;
    int src, dst;
    if (i < E) { src = ei[i]; dst = ei[E + i]; }
    else       { src = dst = i - E; }
    int pos = atomicAdd(&cursor[dst], 1);
    csr_src[pos] = src;
    csr_eid[pos] = i;
}

// ---------- fused per-dst attention (bf16 features), unroll-4 online softmax ----------
__global__ __launch_bounds__(256) void fused_attn(const ushort* __restrict__ xl,
                                                  const ushort* __restrict__ xr,
                                                  const int* __restrict__ rowptr,
                                                  const int* __restrict__ csr_src,
                                                  const int* __restrict__ csr_eid,
                                                  const float* __restrict__ att,
                                                  float* __restrict__ alpha_raw,
                                                  float* __restrict__ msum,   // [2*N*NH]
                                                  const float* __restrict__ bias,
                                                  const float* __restrict__ g,
                                                  const float* __restrict__ be,
                                                  const float* __restrict__ bm,
                                                  const float* __restrict__ bv,
                                                  ushort* __restrict__ hout, int N)
{
    int n = (blockIdx.x * 256 + threadIdx.x) >> 6;
    int lane = threadIdx.x & 63;
    if (n >= N) return;
    int head = lane >> 4, sub = lane & 15;
    const size_t foff = (size_t)head * HID + sub * 8;

    float xrv[8], atv[8];
    ubf8(xr + (size_t)n * FEAT + foff, xrv);
    {
        const float4* a4 = (const float4*)(att + foff);
        float4 t0 = a4[0], t1 = a4[1];
        atv[0]=t0.x; atv[1]=t0.y; atv[2]=t0.z; atv[3]=t0.w;
        atv[4]=t1.x; atv[5]=t1.y; atv[6]=t1.z; atv[7]=t1.w;
    }

    float mrun = -1e30f, den = 0.f, acc[8] = {};
    int beg = rowptr[n], end = rowptr[n + 1];
    int k = beg;

    for (; k + 3 < end; k += 4) {
        int s0 = csr_src[k],     s1 = csr_src[k + 1];
        int s2 = csr_src[k + 2], s3 = csr_src[k + 3];
        int e0 = csr_eid[k],     e1 = csr_eid[k + 1];
        int e2 = csr_eid[k + 2], e3 = csr_eid[k + 3];

        float xv0[8], xv1[8], xv2[8], xv3[8];
        ubf8(xl + (size_t)s0 * FEAT + foff, xv0);
        ubf8(xl + (size_t)s1 * FEAT + foff, xv1);
        ubf8(xl + (size_t)s2 * FEAT + foff, xv2);
        ubf8(xl + (size_t)s3 * FEAT + foff, xv3);

        float l0 = 0.f, l1 = 0.f, l2 = 0.f, l3 = 0.f;
        #pragma unroll
        for (int j = 0; j < 8; ++j) {
            float t0 = xv0[j] + xrv[j]; t0 = (t0 > 0.f) ? t0 : NEG_SLOPE * t0;
            float t1 = xv1[j] + xrv[j]; t1 = (t1 > 0.f) ? t1 : NEG_SLOPE * t1;
            float t2 = xv2[j] + xrv[j]; t2 = (t2 > 0.f) ? t2 : NEG_SLOPE * t2;
            float t3 = xv3[j] + xrv[j]; t3 = (t3 > 0.f) ? t3 : NEG_SLOPE * t3;
            l0 += t0 * atv[j]; l1 += t1 * atv[j];
            l2 += t2 * atv[j]; l3 += t3 * atv[j];
        }
        #pragma unroll
        for (int off = 1; off < 16; off <<= 1) {
            l0 += __shfl_xor(l0, off, 64);
            l1 += __shfl_xor(l1, off, 64);
            l2 += __shfl_xor(l2, off, 64);
            l3 += __shfl_xor(l3, off, 64);
        }
        if (sub == 0) {
            alpha_raw[(size_t)e0 * NH + head] = l0;
            alpha_raw[(size_t)e1 * NH + head] = l1;
            alpha_raw[(size_t)e2 * NH + head] = l2;
            alpha_raw[(size_t)e3 * NH + head] = l3;
        }
        float bmax = fmaxf(fmaxf(l0, l1), fmaxf(l2, l3));
        if (bmax > mrun) {
            float sc = __expf(mrun - bmax);
            den *= sc;
            #pragma unroll
            for (int j = 0; j < 8; ++j) acc[j] *= sc;
            mrun = bmax;
        }
        float w0 = __expf(l0 - mrun), w1 = __expf(l1 - mrun);
        float w2 = __expf(l2 - mrun), w3 = __expf(l3 - mrun);
        den += (w0 + w1) + (w2 + w3);
        #pragma unroll
        for (int j = 0; j < 8; ++j)
            acc[j] += (w0 * xv0[j] + w1 * xv1[j]) + (w2 * xv2[j] + w3 * xv3[j]);
    }

    for (; k < end; ++k) {
        int src = csr_src[k];
        int eid = csr_eid[k];
        float xv[8];
        ubf8(xl + (size_t)src * FEAT + foff, xv);
        float s = 0.f;
        #pragma unroll
        for (int j = 0; j < 8; ++j) {
            float t = xv[j] + xrv[j];
            t = (t > 0.f) ? t : NEG_SLOPE * t;
            s += t * atv[j];
        }
        #pragma unroll
        for (int off = 1; off < 16; off <<= 1) s += __shfl_xor(s, off, 64);
        if (sub == 0) alpha_raw[(size_t)eid * NH + head] = s;
        if (s > mrun) {
            float sc = __expf(mrun - s);
            den *= sc;
            #pragma unroll
            for (int j = 0; j < 8; ++j) acc[j] *= sc;
            mrun = s;
        }
        float e = __expf(s - mrun);
        den += e;
        #pragma unroll
        for (int j = 0; j < 8; ++j) acc[j] += e * xv[j];
    }

    if (sub == 0) {
        msum[n * NH + head] = mrun;
        msum[(size_t)N * NH + n * NH + head] = den;
    }
    float inv = 1.f / (den + 1e-16f);
    float t8[8];
    #pragma unroll
    for (int j = 0; j < 8; ++j) {
        float t = acc[j] * inv;
        t += __shfl_xor(t, 16, 64);
        t += __shfl_xor(t, 32, 64);
        t8[j] = t;
    }
    if (head == 0) {
        uint4 o;
        unsigned w[4];
        #pragma unroll
        for (int q = 0; q < 4; ++q) {
            float s0, s1;
            {
                int c = sub * 8 + 2 * q;
                float s = t8[2 * q] * 0.25f + bias[c];
                float bn = (s - bm[c]) * rsqrtf(bv[c] + BN_EPS) * g[c] + be[c];
                s0 = fmaxf(bn, 0.f);
            }
            {
                int c = sub * 8 + 2 * q + 1;
                float s = t8[2 * q + 1] * 0.25f + bias[c];
                float bn = (s - bm[c]) * rsqrtf(bv[c] + BN_EPS) * g[c] + be[c];
                s1 = fmaxf(bn, 0.f);
            }
            w[q] = (unsigned)f2bf(s0) | ((unsigned)f2bf(s1) << 16);
        }
        o.x = w[0]; o.y = w[1]; o.z = w[2]; o.w = w[3];
        *(uint4*)(hout + (size_t)n * HID + sub * 8) = o;
    }
}

// ---------- finalize alpha: exp(logit - m[dst]) / den[dst] ----------
__global__ __launch_bounds__(256) void alpha_finalize(float* __restrict__ alpha,
                                                      const int* __restrict__ ei,
                                                      const float* __restrict__ msum,
                                                      int N, int E, int Etot)
{
    int i = blockIdx.x * 256 + threadIdx.x;
    if (i >= Etot * NH) return;
    int e = i >> 2, h = i & 3;
    int dst = (e < E) ? ei[E + e] : (e - E);
    float m = msum[dst * NH + h];
    float den = msum[(size_t)N * NH + dst * NH + h];
    alpha[i] = __expf(alpha[i] - m) / (den + 1e-16f);
}

// ---------- final linear + relu + sigmoid (bf16 h) ----------
__global__ __launch_bounds__(256) void final_lin(const ushort* __restrict__ h,
                                                 const float* __restrict__ W,
                                                 const float* __restrict__ b,
                                                 float* __restrict__ out, int N)
{
    int gw = (blockIdx.x * 256 + threadIdx.x) >> 6;
    int lane = threadIdx.x & 63;
    if (gw >= N) return;
    unsigned q = *(const unsigned*)(h + (size_t)gw * HID + lane * 2);
    float h0 = __uint_as_float(q << 16);
    float h1 = __uint_as_float(q & 0xffff0000u);
    float s = h0 * W[lane * 2] + h1 * W[lane * 2 + 1];
    #pragma unroll
    for (int off = 1; off < 64; off <<= 1) s += __shfl_xor(s, off, 64);
    if (lane == 0) {
        float z = fmaxf(s + b[0], 0.f);
        out[gw] = 1.f / (1.f + expf(-z));
    }
}

extern "C" void kernel_launch(void* const* d_in, const int* in_sizes, int n_in,
                              void* d_out, int out_size, void* d_ws, size_t ws_size,
                              hipStream_t stream)
{
    const float* x    = (const float*)d_in[0];
    const int*   ei   = (const int*)d_in[1];
    const float* Wl1  = (const float*)d_in[2];
    const float* Wr1  = (const float*)d_in[3];
    const float* att1 = (const float*)d_in[4];
    const float* b1   = (const float*)d_in[5];
    const float* Wl2  = (const float*)d_in[6];
    const float* Wr2  = (const float*)d_in[7];
    const float* att2 = (const float*)d_in[8];
    const float* b2   = (const float*)d_in[9];
    const float* g1   = (const float*)d_in[10];
    const float* be1  = (const float*)d_in[11];
    const float* m1   = (const float*)d_in[12];
    const float* v1   = (const float*)d_in[13];
    const float* g2   = (const float*)d_in[14];
    const float* be2  = (const float*)d_in[15];
    const float* m2   = (const float*)d_in[16];
    const float* v2   = (const float*)d_in[17];
    const float* Wlin = (const float*)d_in[18];
    const float* blin = (const float*)d_in[19];

    const int IN_C = 256;
    const int N = in_sizes[0] / IN_C;       // 10000
    const int E = in_sizes[1] / 2;          // 320000
    const int Etot = E + N;                 // with self loops

    float* out    = (float*)d_out;          // [N]
    float* alpha1 = out + N;                // [Etot*NH]
    float* alpha2 = alpha1 + (size_t)Etot * NH;

    // workspace layout (bytes)
    char* wsb = (char*)d_ws;
    ushort* xbf   = (ushort*)wsb;                       wsb += (size_t)N * IN_C * 2;
    ushort* xlbf  = (ushort*)wsb;                       wsb += (size_t)N * FEAT * 2;
    ushort* xrbf  = (ushort*)wsb;                       wsb += (size_t)N * FEAT * 2;
    ushort* hbbf  = (ushort*)wsb;                       wsb += (size_t)N * HID * 2;
    ushort* wt1l  = (ushort*)wsb;                       wsb += (size_t)FEAT * IN_C * 2;
    ushort* wt1r  = (ushort*)wsb;                       wsb += (size_t)FEAT * IN_C * 2;
    ushort* wt2l  = (ushort*)wsb;                       wsb += (size_t)FEAT * HID * 2;
    ushort* wt2r  = (ushort*)wsb;                       wsb += (size_t)FEAT * HID * 2;
    float*  msum  = (float*)wsb;                        wsb += (size_t)N * NH * 2 * 4;
    int*    deg    = (int*)wsb;                         wsb += (size_t)N * 4;
    int*    cursor = (int*)wsb;                         wsb += (size_t)N * 4;
    int*    rowptr = (int*)wsb;                         wsb += (size_t)(N + 1) * 4;
    int*    csrsrc = (int*)wsb;                         wsb += (size_t)Etot * 4;
    int*    csreid = (int*)wsb;

    dim3 blk(256);
    dim3 gemm_grid((N + 127) / 128, FEAT / 64);
    int eh_blocks = (Etot * NH + 255) / 256;
    int node_wave_blocks = (N + 3) / 4;
    int etot_blocks = (Etot + 255) / 256;

    // ---- casts ----
    cast_bf16<<<(N * IN_C / 4 + 255) / 256, blk, 0, stream>>>(x, xbf, N * IN_C);
    transpose_cast<<<dim3(IN_C / 32, FEAT / 32), blk, 0, stream>>>(Wl1, wt1l, IN_C, FEAT);
    transpose_cast<<<dim3(IN_C / 32, FEAT / 32), blk, 0, stream>>>(Wr1, wt1r, IN_C, FEAT);
    transpose_cast<<<dim3(HID / 32, FEAT / 32), blk, 0, stream>>>(Wl2, wt2l, HID, FEAT);
    transpose_cast<<<dim3(HID / 32, FEAT / 32), blk, 0, stream>>>(Wr2, wt2r, HID, FEAT);

    // ---- CSR build (shared by both layers) ----
    hipMemsetAsync(deg, 0, (size_t)N * sizeof(int), stream);
    csr_count<<<etot_blocks, blk, 0, stream>>>(ei, deg, E, Etot);
    scan_rowptr<<<1, 1024, 0, stream>>>(deg, rowptr, cursor, N);
    csr_fill<<<etot_blocks, blk, 0, stream>>>(ei, cursor, csrsrc, csreid, E, Etot);

    // ================= layer 1 =================
    gemm_bf16<<<gemm_grid, blk, 0, stream>>>(xbf, wt1l, xlbf, N, FEAT, IN_C);
    gemm_bf16<<<gemm_grid, blk, 0, stream>>>(xbf, wt1r, xrbf, N, FEAT, IN_C);
    fused_attn<<<node_wave_blocks, blk, 0, stream>>>(xlbf, xrbf, rowptr, csrsrc, csreid,
                                                     att1, alpha1, msum,
                                                     b1, g1, be1, m1, v1, hbbf, N);
    alpha_finalize<<<eh_blocks, blk, 0, stream>>>(alpha1, ei, msum, N, E, Etot);

    // ================= layer 2 =================
    gemm_bf16<<<gemm_grid, blk, 0, stream>>>(hbbf, wt2l, xlbf, N, FEAT, HID);
    gemm_bf16<<<gemm_grid, blk, 0, stream>>>(hbbf, wt2r, xrbf, N, FEAT, HID);
    fused_attn<<<node_wave_blocks, blk, 0, stream>>>(xlbf, xrbf, rowptr, csrsrc, csreid,
                                                     att2, alpha2, msum,
                                                     b2, g2, be2, m2, v2, hbbf, N);
    alpha_finalize<<<eh_blocks, blk, 0, stream>>>(alpha2, ei, msum, N, E, Etot);

    // ================= head =================
    final_lin<<<node_wave_blocks, blk, 0, stream>>>(hbbf, Wlin, blin, out, N);
}